// Round 2
// baseline (13028.059 us; speedup 1.0000x reference)
//
#include <hip/hip_runtime.h>
#include <hip/hip_bf16.h>

// Geometry (fixed by the problem): B=1, C=8, D=H=W=128.
constexpr int DD  = 128;
constexpr int HH  = 128;
constexpr int WW  = 128;
constexpr int HW2 = HH * WW;          // 16384
constexpr int DHW = DD * HH * WW;     // 2097152
constexpr int CIN = 8;

// ---------------------------------------------------------------------------
// Kernel 1: conv3d(x, w1) + bias + ReLU  (8 -> 8 channels, 3x3x3, SAME).
// ONE voxel per thread: acc[8] keeps VGPR low -> high occupancy (R1 showed
// VGPR=256 + scratch spills at 4 voxels/thread).
// ---------------------------------------------------------------------------
__global__ __launch_bounds__(256) void k_conv1(
    const float* __restrict__ x, const float* __restrict__ w1,
    const float* __restrict__ b1, float* __restrict__ hb) {
  __shared__ float ws[8 * 27 * 8];  // [(ci*27+tap)*8 + co]
  __shared__ float bs[8];
  const int tid = threadIdx.x;
  for (int i = tid; i < 8 * 8 * 27; i += 256) {
    int co = i / 216;              // w1 layout: [co][ci][kd][kh][kw]
    int r  = i - co * 216;         // r = ci*27 + tap
    ws[r * 8 + co] = w1[i];
  }
  if (tid < 8) bs[tid] = b1[tid];
  __syncthreads();

  const int idx = blockIdx.x * 256 + tid;   // [0, DHW)
  const int d  = idx >> 14;
  const int rem = idx & (HW2 - 1);
  const int hh = rem >> 7;
  const int ww = rem & 127;

  // (dy,dx) clamped offsets + validity bits
  int off2[9];
  unsigned m2 = 0;
  {
    int j = 0;
#pragma unroll
    for (int dy = -1; dy <= 1; ++dy) {
      int yy = hh + dy; bool oky = (unsigned)yy < 128u; int yc = oky ? yy : hh;
#pragma unroll
      for (int dx = -1; dx <= 1; ++dx) {
        int xx = ww + dx; bool okx = (unsigned)xx < 128u; int xc = okx ? xx : ww;
        off2[j] = yc * WW + xc;
        if (oky && okx) m2 |= (1u << j);
        ++j;
      }
    }
  }

  float acc[8];
#pragma unroll
  for (int co = 0; co < 8; ++co) acc[co] = bs[co];

  for (int ci = 0; ci < CIN; ++ci) {
    const float* base = x + (size_t)ci * DHW;
#pragma unroll
    for (int dz = -1; dz <= 1; ++dz) {
      int zz = d + dz;
      bool okz = (unsigned)zz < 128u;
      int zoff = (okz ? zz : d) * HW2;
      const int tapbase = ci * 27 + (dz + 1) * 9;
#pragma unroll
      for (int j = 0; j < 9; ++j) {
        float t = base[zoff + off2[j]];
        float val = (okz && ((m2 >> j) & 1u)) ? t : 0.0f;
        const float* wrow = &ws[(tapbase + j) * 8];
#pragma unroll
        for (int co = 0; co < 8; ++co)
          acc[co] = fmaf(val, wrow[co], acc[co]);
      }
    }
  }

#pragma unroll
  for (int co = 0; co < 8; ++co)
    hb[(size_t)co * DHW + idx] = fmaxf(acc[co], 0.0f);
}

// ---------------------------------------------------------------------------
// Kernel 2: conv3d(h, w2) (8 -> 27 channels) fused with L1 normalization;
// writes normalized per-voxel weights as bf16. ONE voxel per thread (acc[27]).
// ---------------------------------------------------------------------------
__global__ __launch_bounds__(256) void k_conv2(
    const float* __restrict__ hb, const float* __restrict__ w2,
    __hip_bfloat16* __restrict__ wn) {
  __shared__ float ws[8 * 27 * 27];  // [(ci*27+tap)*27 + oc]
  const int tid = threadIdx.x;
  for (int i = tid; i < 27 * 8 * 27; i += 256) {
    int oc = i / 216;              // w2 layout: [oc][ci][kd][kh][kw]
    int r  = i - oc * 216;         // r = ci*27 + tap
    ws[r * 27 + oc] = w2[i];
  }
  __syncthreads();

  const int idx = blockIdx.x * 256 + tid;
  const int d  = idx >> 14;
  const int rem = idx & (HW2 - 1);
  const int hh = rem >> 7;
  const int ww = rem & 127;

  int off2[9];
  unsigned m2 = 0;
  {
    int j = 0;
#pragma unroll
    for (int dy = -1; dy <= 1; ++dy) {
      int yy = hh + dy; bool oky = (unsigned)yy < 128u; int yc = oky ? yy : hh;
#pragma unroll
      for (int dx = -1; dx <= 1; ++dx) {
        int xx = ww + dx; bool okx = (unsigned)xx < 128u; int xc = okx ? xx : ww;
        off2[j] = yc * WW + xc;
        if (oky && okx) m2 |= (1u << j);
        ++j;
      }
    }
  }

  float acc[27];
#pragma unroll
  for (int oc = 0; oc < 27; ++oc) acc[oc] = 0.0f;

  for (int ci = 0; ci < CIN; ++ci) {
    const float* base = hb + (size_t)ci * DHW;
#pragma unroll
    for (int dz = -1; dz <= 1; ++dz) {
      int zz = d + dz;
      bool okz = (unsigned)zz < 128u;
      int zoff = (okz ? zz : d) * HW2;
      const int tapbase = ci * 27 + (dz + 1) * 9;
#pragma unroll
      for (int j = 0; j < 9; ++j) {
        float t = base[zoff + off2[j]];
        float val = (okz && ((m2 >> j) & 1u)) ? t : 0.0f;
        const float* wrow = &ws[(tapbase + j) * 27];
#pragma unroll
        for (int oc = 0; oc < 27; ++oc)
          acc[oc] = fmaf(val, wrow[oc], acc[oc]);
      }
    }
  }

  float n = 0.0f;
#pragma unroll
  for (int oc = 0; oc < 27; ++oc) n += fabsf(acc[oc]);
  float s = 1.0f / fmaxf(n, 1e-12f);
#pragma unroll
  for (int oc = 0; oc < 27; ++oc)
    wn[(size_t)oc * DHW + idx] = __float2bfloat16(acc[oc] * s);
}

// ---------------------------------------------------------------------------
// Kernel 3: one adaptive 3x3x3 conv pass: out[c,p] = sum_t in[c, p+off(t)] * wn[t,p]
// ---------------------------------------------------------------------------
__global__ __launch_bounds__(256) void k_adapt(
    const float* __restrict__ in, const __hip_bfloat16* __restrict__ wn,
    float* __restrict__ out) {
  const int idx = blockIdx.x * 256 + threadIdx.x;  // [0, DHW)
  const int d = idx >> 14;
  const int rem = idx & (HW2 - 1);
  const int hh = rem >> 7;
  const int ww = rem & 127;

  int offs[27];
  unsigned mask = 0;
  {
    int t = 0;
#pragma unroll
    for (int dz = -1; dz <= 1; ++dz) {
      int zz = d + dz; bool okz = (unsigned)zz < 128u; int zc = okz ? zz : d;
#pragma unroll
      for (int dy = -1; dy <= 1; ++dy) {
        int yy = hh + dy; bool oky = (unsigned)yy < 128u; int yc = oky ? yy : hh;
#pragma unroll
        for (int dx = -1; dx <= 1; ++dx) {
          int xx = ww + dx; bool okx = (unsigned)xx < 128u; int xc = okx ? xx : ww;
          offs[t] = (zc * HH + yc) * WW + xc;
          if (okz && oky && okx) mask |= (1u << t);
          ++t;
        }
      }
    }
  }

  float wt[27];
#pragma unroll
  for (int t = 0; t < 27; ++t)
    wt[t] = __bfloat162float(wn[(size_t)t * DHW + idx]);

  for (int c = 0; c < 8; ++c) {
    const float* base = in + (size_t)c * DHW;
    float a = 0.0f;
#pragma unroll
    for (int t = 0; t < 27; ++t) {
      float v = base[offs[t]];
      v = ((mask >> t) & 1u) ? v : 0.0f;
      a = fmaf(v, wt[t], a);
    }
    out[(size_t)c * DHW + idx] = a;
  }
}

// ---------------------------------------------------------------------------
extern "C" void kernel_launch(void* const* d_in, const int* in_sizes, int n_in,
                              void* d_out, int out_size, void* d_ws, size_t ws_size,
                              hipStream_t stream) {
  const float* x  = (const float*)d_in[0];  // [1,8,128,128,128]
  const float* w1 = (const float*)d_in[1];  // [8,8,3,3,3]
  const float* b1 = (const float*)d_in[2];  // [8]
  const float* w2 = (const float*)d_in[3];  // [27,8,3,3,3]
  float* out = (float*)d_out;

  // Workspace layout: hb (64 MiB fp32) | wn (108 MiB bf16) | tb (64 MiB fp32)
  char* ws = (char*)d_ws;
  float* hb = (float*)ws;
  __hip_bfloat16* wn = (__hip_bfloat16*)(ws + (size_t)8 * DHW * 4);
  float* tb = (float*)(ws + (size_t)8 * DHW * 4 + (size_t)27 * DHW * 2);

  dim3 blk(256);
  k_conv1<<<DHW / 256, blk, 0, stream>>>(x, w1, b1, hb);
  k_conv2<<<DHW / 256, blk, 0, stream>>>(hb, w2, wn);
  k_adapt<<<DHW / 256, blk, 0, stream>>>(x,  wn, tb);
  k_adapt<<<DHW / 256, blk, 0, stream>>>(tb, wn, hb);
  k_adapt<<<DHW / 256, blk, 0, stream>>>(hb, wn, out);
}

// Round 3
// 2026.224 us; speedup vs baseline: 6.4297x; 6.4297x over previous
//
#include <hip/hip_runtime.h>
#include <hip/hip_bf16.h>

// Geometry (fixed by the problem): B=1, C=8, D=H=W=128.
constexpr int HH  = 128;
constexpr int WW  = 128;
constexpr int HW2 = HH * WW;          // 16384
constexpr int DHW = 128 * HH * WW;    // 2097152
constexpr int CIN = 8;

// ---------------------------------------------------------------------------
// Prep: transpose weights so that for a fixed (ci,tap) the output channels are
// contiguous -> one uniform (scalar) row read per tap.
//   wT1[(ci*27+tap)*8  + co] = w1[co][ci][tap]   (rows 32B)
//   wT2[(ci*27+tap)*32 + oc] = w2[oc][ci][tap]   (rows 128B, padded 27->32)
// ---------------------------------------------------------------------------
__global__ __launch_bounds__(256) void k_prep(
    const float* __restrict__ w1, const float* __restrict__ w2,
    float* __restrict__ wT1, float* __restrict__ wT2) {
  int i = blockIdx.x * 256 + threadIdx.x;
  if (i < 8 * 27 * 27) {            // 5832: wT2
    int oc = i % 27;
    int r  = i / 27;                // r = ci*27 + tap
    int ci = r / 27, tap = r % 27;
    wT2[r * 32 + oc] = w2[(oc * 8 + ci) * 27 + tap];
  }
  int j = i - 8 * 27 * 27;
  if (j >= 0 && j < 8 * 27 * 8) {   // 1728: wT1
    int co = j % 8;
    int r  = j / 8;
    int ci = r / 27, tap = r % 27;
    wT1[r * 8 + co] = w1[(co * 8 + ci) * 27 + tap];
  }
}

// ---------------------------------------------------------------------------
// Kernel 1: conv3d(x, w1) + bias + ReLU (8 -> 8). 1 voxel/thread.
// Weights via uniform scalar loads (readfirstlane-pinned row index).
// #pragma unroll 1 on ci: stops the unroller/scheduler from hoisting all 216
// val loads (the R1/R2 spill cause: VGPR=256 + GBs of scratch traffic).
// ---------------------------------------------------------------------------
__global__ __launch_bounds__(256) void k_conv1(
    const float* __restrict__ x, const float* __restrict__ wT1,
    const float* __restrict__ b1, float* __restrict__ hb) {
  const int idx = blockIdx.x * 256 + threadIdx.x;   // [0, DHW)
  const int d   = idx >> 14;
  const int rem = idx & (HW2 - 1);
  const int hh  = rem >> 7;
  const int ww  = rem & 127;

  int off2[9];
  unsigned m2 = 0;
  {
    int j = 0;
#pragma unroll
    for (int dy = -1; dy <= 1; ++dy) {
      int yy = hh + dy; bool oky = (unsigned)yy < 128u; int yc = oky ? yy : hh;
#pragma unroll
      for (int dx = -1; dx <= 1; ++dx) {
        int xx = ww + dx; bool okx = (unsigned)xx < 128u; int xc = okx ? xx : ww;
        off2[j] = yc * WW + xc;
        if (oky && okx) m2 |= (1u << j);
        ++j;
      }
    }
  }

  float acc[8];
#pragma unroll
  for (int co = 0; co < 8; ++co) acc[co] = b1[co];  // uniform load

#pragma unroll 1
  for (int ci = 0; ci < CIN; ++ci) {
    const float* base = x + (size_t)ci * DHW;
#pragma unroll
    for (int dz = -1; dz <= 1; ++dz) {
      int zz = d + dz;
      bool okz = (unsigned)zz < 128u;
      int zoff = (okz ? zz : d) * HW2;
#pragma unroll
      for (int j = 0; j < 9; ++j) {
        float t = base[zoff + off2[j]];
        float val = (okz && ((m2 >> j) & 1u)) ? t : 0.0f;
        const float* wr =
            wT1 + __builtin_amdgcn_readfirstlane((ci * 27 + (dz + 1) * 9 + j) * 8);
#pragma unroll
        for (int co = 0; co < 8; ++co)
          acc[co] = fmaf(val, wr[co], acc[co]);
      }
    }
  }

#pragma unroll
  for (int co = 0; co < 8; ++co)
    hb[(size_t)co * DHW + idx] = fmaxf(acc[co], 0.0f);
}

// ---------------------------------------------------------------------------
// Kernel 2: conv3d(h, w2) (8 -> 27) + fused L1 norm; bf16 weight-field output.
// Same structure: scalar weight rows, unroll-1 ci, acc[27] in VGPRs.
// ---------------------------------------------------------------------------
__global__ __launch_bounds__(256) void k_conv2(
    const float* __restrict__ hb, const float* __restrict__ wT2,
    __hip_bfloat16* __restrict__ wn) {
  const int idx = blockIdx.x * 256 + threadIdx.x;
  const int d   = idx >> 14;
  const int rem = idx & (HW2 - 1);
  const int hh  = rem >> 7;
  const int ww  = rem & 127;

  int off2[9];
  unsigned m2 = 0;
  {
    int j = 0;
#pragma unroll
    for (int dy = -1; dy <= 1; ++dy) {
      int yy = hh + dy; bool oky = (unsigned)yy < 128u; int yc = oky ? yy : hh;
#pragma unroll
      for (int dx = -1; dx <= 1; ++dx) {
        int xx = ww + dx; bool okx = (unsigned)xx < 128u; int xc = okx ? xx : ww;
        off2[j] = yc * WW + xc;
        if (oky && okx) m2 |= (1u << j);
        ++j;
      }
    }
  }

  float acc[27];
#pragma unroll
  for (int oc = 0; oc < 27; ++oc) acc[oc] = 0.0f;

#pragma unroll 1
  for (int ci = 0; ci < CIN; ++ci) {
    const float* base = hb + (size_t)ci * DHW;
#pragma unroll
    for (int dz = -1; dz <= 1; ++dz) {
      int zz = d + dz;
      bool okz = (unsigned)zz < 128u;
      int zoff = (okz ? zz : d) * HW2;
#pragma unroll
      for (int j = 0; j < 9; ++j) {
        float t = base[zoff + off2[j]];
        float val = (okz && ((m2 >> j) & 1u)) ? t : 0.0f;
        const float* wr =
            wT2 + __builtin_amdgcn_readfirstlane((ci * 27 + (dz + 1) * 9 + j) * 32);
#pragma unroll
        for (int oc = 0; oc < 27; ++oc)
          acc[oc] = fmaf(val, wr[oc], acc[oc]);
      }
    }
  }

  float n = 0.0f;
#pragma unroll
  for (int oc = 0; oc < 27; ++oc) n += fabsf(acc[oc]);
  float s = 1.0f / fmaxf(n, 1e-12f);
#pragma unroll
  for (int oc = 0; oc < 27; ++oc)
    wn[(size_t)oc * DHW + idx] = __float2bfloat16(acc[oc] * s);
}

// ---------------------------------------------------------------------------
// Kernel 3: one adaptive 3x3x3 conv pass: out[c,p] = sum_t in[c,p+off(t)]*wn[t,p]
// ---------------------------------------------------------------------------
__global__ __launch_bounds__(256) void k_adapt(
    const float* __restrict__ in, const __hip_bfloat16* __restrict__ wn,
    float* __restrict__ out) {
  const int idx = blockIdx.x * 256 + threadIdx.x;  // [0, DHW)
  const int d = idx >> 14;
  const int rem = idx & (HW2 - 1);
  const int hh = rem >> 7;
  const int ww = rem & 127;

  int offs[27];
  unsigned mask = 0;
  {
    int t = 0;
#pragma unroll
    for (int dz = -1; dz <= 1; ++dz) {
      int zz = d + dz; bool okz = (unsigned)zz < 128u; int zc = okz ? zz : d;
#pragma unroll
      for (int dy = -1; dy <= 1; ++dy) {
        int yy = hh + dy; bool oky = (unsigned)yy < 128u; int yc = oky ? yy : hh;
#pragma unroll
        for (int dx = -1; dx <= 1; ++dx) {
          int xx = ww + dx; bool okx = (unsigned)xx < 128u; int xc = okx ? xx : ww;
          offs[t] = (zc * HH + yc) * WW + xc;
          if (okz && oky && okx) mask |= (1u << t);
          ++t;
        }
      }
    }
  }

  float wt[27];
#pragma unroll
  for (int t = 0; t < 27; ++t)
    wt[t] = __bfloat162float(wn[(size_t)t * DHW + idx]);

#pragma unroll 1
  for (int c = 0; c < 8; ++c) {
    const float* base = in + (size_t)c * DHW;
    float a = 0.0f;
#pragma unroll
    for (int t = 0; t < 27; ++t) {
      float v = base[offs[t]];
      v = ((mask >> t) & 1u) ? v : 0.0f;
      a = fmaf(v, wt[t], a);
    }
    out[(size_t)c * DHW + idx] = a;
  }
}

// ---------------------------------------------------------------------------
extern "C" void kernel_launch(void* const* d_in, const int* in_sizes, int n_in,
                              void* d_out, int out_size, void* d_ws, size_t ws_size,
                              hipStream_t stream) {
  const float* x  = (const float*)d_in[0];  // [1,8,128,128,128]
  const float* w1 = (const float*)d_in[1];  // [8,8,3,3,3]
  const float* b1 = (const float*)d_in[2];  // [8]
  const float* w2 = (const float*)d_in[3];  // [27,8,3,3,3]
  float* out = (float*)d_out;

  // Workspace: hb 64MiB | wn bf16 108MiB | tb 64MiB | wT2 27648B | wT1 6912B
  char* ws = (char*)d_ws;
  float* hb = (float*)ws;
  __hip_bfloat16* wn = (__hip_bfloat16*)(ws + (size_t)8 * DHW * 4);
  float* tb = (float*)(ws + (size_t)8 * DHW * 4 + (size_t)27 * DHW * 2);
  float* wT2 = (float*)(ws + (size_t)8 * DHW * 4 + (size_t)27 * DHW * 2 +
                        (size_t)8 * DHW * 4);
  float* wT1 = wT2 + 8 * 27 * 32;

  dim3 blk(256);
  k_prep<<<32, blk, 0, stream>>>(w1, w2, wT1, wT2);
  k_conv1<<<DHW / 256, blk, 0, stream>>>(x, wT1, b1, hb);
  k_conv2<<<DHW / 256, blk, 0, stream>>>(hb, wT2, wn);
  k_adapt<<<DHW / 256, blk, 0, stream>>>(x,  wn, tb);
  k_adapt<<<DHW / 256, blk, 0, stream>>>(tb, wn, hb);
  k_adapt<<<DHW / 256, blk, 0, stream>>>(hb, wn, out);
}

// Round 4
// 1190.874 us; speedup vs baseline: 10.9399x; 1.7015x over previous
//
#include <hip/hip_runtime.h>
#include <hip/hip_bf16.h>

// Geometry (fixed): B=1, C=8, D=H=W=128.
constexpr int HH  = 128;
constexpr int WW  = 128;
constexpr int HW2 = 16384;
constexpr int DHW = 2097152;
constexpr int CIN = 8;

// conv2-MFMA staging geometry
constexpr int PK = 104;   // LDS kr pitch (elems); mult of 8 -> b128-aligned; 52 words -> <=2-way banks
constexpr int XT = 130;   // staged x extent: x = -1 .. 128

typedef short bf16x8 __attribute__((ext_vector_type(8)));  // 8 bf16 = 4 VGPR
typedef float f32x4  __attribute__((ext_vector_type(4)));

// ---------------------------------------------------------------------------
// Prep: (a) Wpack: w2 -> MFMA A-fragment order, bf16, dx-split.
//   k = (ci,dzrel,dyrel) packed kr = ci*9+dzrel*3+dyrel in [0,72), pad 96.
//   Wpack[((dx*3+s)*2+Mt)*512 + lane*8 + j] = W[oc = Mt*16+(lane&15)]
//                                              [kr = s*32+(lane>>4)*8+j]
// (b) wT1: w1 transposed to [ci*27+tap][co] rows for conv1 scalar reads.
// ---------------------------------------------------------------------------
__global__ __launch_bounds__(256) void k_prep(
    const float* __restrict__ w1, const float* __restrict__ w2,
    float* __restrict__ wT1, unsigned short* __restrict__ Wpack) {
  int i = blockIdx.x * 256 + threadIdx.x;
  if (i < 9216) {
    int j = i & 7;
    int lane = (i >> 3) & 63;
    int Mt = (i >> 9) & 1;
    int g = i >> 10;          // dx*3 + s
    int s = g % 3, dx = g / 3;
    int oc = Mt * 16 + (lane & 15);
    int kr = s * 32 + (lane >> 4) * 8 + j;
    float w = 0.f;
    if (oc < 27 && kr < 72) {
      int ci = kr / 9, rm = kr % 9, dzr = rm / 3, dyr = rm % 3;
      w = w2[(oc * 8 + ci) * 27 + dzr * 9 + dyr * 3 + dx];
    }
    __hip_bfloat16 hv = __float2bfloat16(w);
    Wpack[i] = *(unsigned short*)&hv;
  }
  int jj = i - 9216;
  if (jj >= 0 && jj < 1728) {
    int co = jj % 8;
    int r = jj / 8;
    int ci = r / 27, tap = r % 27;
    wT1[r * 8 + co] = w1[(co * 8 + ci) * 27 + tap];
  }
}

// ---------------------------------------------------------------------------
// Kernel 1: conv3d(x, w1) + bias + ReLU (8 -> 8). Scalar-weight FMA structure
// (R3-proven: no spills). Output now bf16 (feeds MFMA conv2 + halves traffic).
// ---------------------------------------------------------------------------
__global__ __launch_bounds__(256) void k_conv1(
    const float* __restrict__ x, const float* __restrict__ wT1,
    const float* __restrict__ b1, __hip_bfloat16* __restrict__ hb) {
  const int idx = blockIdx.x * 256 + threadIdx.x;
  const int d   = idx >> 14;
  const int rem = idx & (HW2 - 1);
  const int hh  = rem >> 7;
  const int ww  = rem & 127;

  int off2[9];
  unsigned m2 = 0;
  {
    int j = 0;
#pragma unroll
    for (int dy = -1; dy <= 1; ++dy) {
      int yy = hh + dy; bool oky = (unsigned)yy < 128u; int yc = oky ? yy : hh;
#pragma unroll
      for (int dx = -1; dx <= 1; ++dx) {
        int xx = ww + dx; bool okx = (unsigned)xx < 128u; int xc = okx ? xx : ww;
        off2[j] = yc * WW + xc;
        if (oky && okx) m2 |= (1u << j);
        ++j;
      }
    }
  }

  float acc[8];
#pragma unroll
  for (int co = 0; co < 8; ++co) acc[co] = b1[co];

#pragma unroll 1
  for (int ci = 0; ci < CIN; ++ci) {
    const float* base = x + (size_t)ci * DHW;
#pragma unroll
    for (int dz = -1; dz <= 1; ++dz) {
      int zz = d + dz;
      bool okz = (unsigned)zz < 128u;
      int zoff = (okz ? zz : d) * HW2;
#pragma unroll
      for (int j = 0; j < 9; ++j) {
        float t = base[zoff + off2[j]];
        float val = (okz && ((m2 >> j) & 1u)) ? t : 0.0f;
        const float* wr =
            wT1 + __builtin_amdgcn_readfirstlane((ci * 27 + (dz + 1) * 9 + j) * 8);
#pragma unroll
        for (int co = 0; co < 8; ++co)
          acc[co] = fmaf(val, wr[co], acc[co]);
      }
    }
  }

#pragma unroll
  for (int co = 0; co < 8; ++co)
    hb[(size_t)co * DHW + idx] = __float2bfloat16(fmaxf(acc[co], 0.0f));
}

// ---------------------------------------------------------------------------
// Kernel 2: conv3d(h, w2) (8 -> 27) + fused L1 norm as implicit-GEMM MFMA.
// Block = one (z,y) row of 128 voxels; 4 waves x 2 N-tiles of 16 voxels.
// LDS: hT[x][kr] x-major transposed stage (kr = ci*9+dz*3+dy, padded to 96)
// so each B-fragment is ONE ds_read_b128. dx handled as 3 GEMM passes via
// shifted x reads. Weights live in VGPRs (fragment-packed by k_prep).
// ---------------------------------------------------------------------------
__global__ __launch_bounds__(256) void k_conv2(
    const __hip_bfloat16* __restrict__ hb,
    const unsigned short* __restrict__ Wpack,
    __hip_bfloat16* __restrict__ wn) {
  __shared__ __align__(16) unsigned short hT[XT * PK];
  const int tid  = threadIdx.x;
  const int lane = tid & 63;
  const int wv   = tid >> 6;
  const int z0 = blockIdx.x >> 7;
  const int y0 = blockIdx.x & 127;

  // Weights -> VGPRs: 18 x bf16x8 (72 VGPR)
  bf16x8 wf[3][3][2];
  {
    const bf16x8* wp = (const bf16x8*)Wpack;
#pragma unroll
    for (int dx = 0; dx < 3; ++dx)
#pragma unroll
      for (int s = 0; s < 3; ++s)
#pragma unroll
        for (int mt = 0; mt < 2; ++mt)
          wf[dx][s][mt] = wp[((dx * 3 + s) * 2 + mt) * 64 + lane];
  }

  // Zero-fill LDS (kr 72..96 pad + boundary cells must be 0, never NaN)
  {
    uint4 z4 = make_uint4(0u, 0u, 0u, 0u);
    uint4* p = (uint4*)hT;
#pragma unroll 1
    for (int i = tid; i < XT * PK / 8; i += 256) p[i] = z4;
  }
  __syncthreads();

  // Stage hT[xi][r]: r = ci*9 + dzrel*3 + dyrel; xi = x+1 (x in [-1,128])
#pragma unroll 1
  for (int c = tid; c < 72 * XT; c += 256) {
    int r  = c / XT;
    int xi = c - r * XT;
    int ci = r / 9, rm = r % 9, dzr = rm / 3, dyr = rm % 3;
    int z = z0 + dzr - 1, y = y0 + dyr - 1, xg = xi - 1;
    unsigned short v = 0;
    if ((unsigned)z < 128u && (unsigned)y < 128u && (unsigned)xg < 128u)
      v = *(const unsigned short*)&hb[((size_t)(ci * 128 + z) * 128 + y) * 128 + xg];
    hT[xi * PK + r] = v;
  }
  __syncthreads();

  // Implicit GEMM: out[oc, x] = sum_dx sum_kr W[oc][kr,dx] * hT[x+dx][kr]
  f32x4 acc[2][2];  // [nt][mt]
#pragma unroll
  for (int nt = 0; nt < 2; ++nt)
#pragma unroll
    for (int mt = 0; mt < 2; ++mt) acc[nt][mt] = (f32x4){0.f, 0.f, 0.f, 0.f};

  const int n = lane & 15;
  const int q = lane >> 4;
  const int xbase = wv * 32 + n;  // + dx gives hT x-index (includes +1 shift)

#pragma unroll
  for (int dx = 0; dx < 3; ++dx) {
#pragma unroll
    for (int s = 0; s < 3; ++s) {
      bf16x8 bfr[2];
#pragma unroll
      for (int nt = 0; nt < 2; ++nt) {
        int off = (xbase + nt * 16 + dx) * PK + s * 32 + q * 8;
        bfr[nt] = *(const bf16x8*)&hT[off];
      }
#pragma unroll
      for (int mt = 0; mt < 2; ++mt)
#pragma unroll
        for (int nt = 0; nt < 2; ++nt)
          acc[nt][mt] = __builtin_amdgcn_mfma_f32_16x16x32_bf16(
              wf[dx][s][mt], bfr[nt], acc[nt][mt], 0, 0, 0);
    }
  }

  // Epilogue: L1 norm over 27 ocs (spread across regs + lane quads) + bf16 store
  const int voxrow = (z0 * 128 + y0) * 128;
#pragma unroll
  for (int nt = 0; nt < 2; ++nt) {
    float ns = 0.f;
#pragma unroll
    for (int r = 0; r < 4; ++r) ns += fabsf(acc[nt][0][r]);
#pragma unroll
    for (int r = 0; r < 4; ++r) {
      int oc = 16 + q * 4 + r;
      ns += (oc < 27) ? fabsf(acc[nt][1][r]) : 0.f;
    }
    ns += __shfl_xor(ns, 16);
    ns += __shfl_xor(ns, 32);
    float sc = 1.f / fmaxf(ns, 1e-12f);
    const int vox = voxrow + wv * 32 + nt * 16 + n;
#pragma unroll
    for (int r = 0; r < 4; ++r) {
      int oc = q * 4 + r;  // < 16 always
      wn[(size_t)oc * DHW + vox] = __float2bfloat16(acc[nt][0][r] * sc);
    }
#pragma unroll
    for (int r = 0; r < 4; ++r) {
      int oc = 16 + q * 4 + r;
      if (oc < 27)
        wn[(size_t)oc * DHW + vox] = __float2bfloat16(acc[nt][1][r] * sc);
    }
  }
}

// ---------------------------------------------------------------------------
// Kernel 3: one adaptive 3x3x3 conv pass (unchanged from R3).
// ---------------------------------------------------------------------------
__global__ __launch_bounds__(256) void k_adapt(
    const float* __restrict__ in, const __hip_bfloat16* __restrict__ wn,
    float* __restrict__ out) {
  const int idx = blockIdx.x * 256 + threadIdx.x;
  const int d = idx >> 14;
  const int rem = idx & (HW2 - 1);
  const int hh = rem >> 7;
  const int ww = rem & 127;

  int offs[27];
  unsigned mask = 0;
  {
    int t = 0;
#pragma unroll
    for (int dz = -1; dz <= 1; ++dz) {
      int zz = d + dz; bool okz = (unsigned)zz < 128u; int zc = okz ? zz : d;
#pragma unroll
      for (int dy = -1; dy <= 1; ++dy) {
        int yy = hh + dy; bool oky = (unsigned)yy < 128u; int yc = oky ? yy : hh;
#pragma unroll
        for (int dx = -1; dx <= 1; ++dx) {
          int xx = ww + dx; bool okx = (unsigned)xx < 128u; int xc = okx ? xx : ww;
          offs[t] = (zc * HH + yc) * WW + xc;
          if (okz && oky && okx) mask |= (1u << t);
          ++t;
        }
      }
    }
  }

  float wt[27];
#pragma unroll
  for (int t = 0; t < 27; ++t)
    wt[t] = __bfloat162float(wn[(size_t)t * DHW + idx]);

#pragma unroll 1
  for (int c = 0; c < 8; ++c) {
    const float* base = in + (size_t)c * DHW;
    float a = 0.0f;
#pragma unroll
    for (int t = 0; t < 27; ++t) {
      float v = base[offs[t]];
      v = ((mask >> t) & 1u) ? v : 0.0f;
      a = fmaf(v, wt[t], a);
    }
    out[(size_t)c * DHW + idx] = a;
  }
}

// ---------------------------------------------------------------------------
extern "C" void kernel_launch(void* const* d_in, const int* in_sizes, int n_in,
                              void* d_out, int out_size, void* d_ws, size_t ws_size,
                              hipStream_t stream) {
  const float* x  = (const float*)d_in[0];
  const float* w1 = (const float*)d_in[1];
  const float* b1 = (const float*)d_in[2];
  const float* w2 = (const float*)d_in[3];
  float* out = (float*)d_out;

  // Workspace: hb bf16 32MiB | wn bf16 108MiB | tb fp32 64MiB | wT1 | Wpack
  char* ws = (char*)d_ws;
  __hip_bfloat16* hb = (__hip_bfloat16*)ws;
  __hip_bfloat16* wn = (__hip_bfloat16*)(ws + (size_t)CIN * DHW * 2);
  float* tb  = (float*)(ws + (size_t)CIN * DHW * 2 + (size_t)27 * DHW * 2);
  float* wT1 = (float*)(ws + (size_t)CIN * DHW * 2 + (size_t)27 * DHW * 2 +
                        (size_t)CIN * DHW * 4);
  unsigned short* Wpack = (unsigned short*)(wT1 + 1728);

  dim3 blk(256);
  k_prep<<<43, blk, 0, stream>>>(w1, w2, wT1, Wpack);
  k_conv1<<<DHW / 256, blk, 0, stream>>>(x, wT1, b1, hb);
  k_conv2<<<128 * 128, blk, 0, stream>>>(hb, Wpack, wn);
  // adaptive ping-pong: x -> out -> tb -> out (d_out doubles as scratch)
  k_adapt<<<DHW / 256, blk, 0, stream>>>(x, wn, out);
  k_adapt<<<DHW / 256, blk, 0, stream>>>(out, wn, tb);
  k_adapt<<<DHW / 256, blk, 0, stream>>>(tb, wn, out);
}

// Round 5
// 923.000 us; speedup vs baseline: 14.1149x; 1.2902x over previous
//
#include <hip/hip_runtime.h>
#include <hip/hip_bf16.h>

// Geometry (fixed): B=1, C=8, D=H=W=128.
constexpr int HH  = 128;
constexpr int WW  = 128;
constexpr int HW2 = 16384;
constexpr int DHW = 2097152;
constexpr int CIN = 8;

// MFMA staging geometry (shared by conv1/conv2)
constexpr int PK = 104;   // LDS kr pitch; mult of 8 -> b128-aligned; <=2-way banks
constexpr int XT = 130;   // staged x extent: x = -1 .. 128

typedef short bf16x8 __attribute__((ext_vector_type(8)));  // 8 bf16 = 4 VGPR
typedef float f32x4  __attribute__((ext_vector_type(4)));

// ---------------------------------------------------------------------------
// Prep: pack both weight tensors into MFMA A-fragment order (bf16, dx-split).
//   kr = ci*9 + dzrel*3 + dyrel in [0,72), padded to 96 (3 K-steps of 32).
//   Wpack2: 9216 ush = [(dx*3+s)*2+Mt][lane][j], oc = Mt*16+(lane&15) (<27)
//   Wpack1: 4608 ush = [dx*3+s][lane][j],        oc = lane&15 (<8)
// ---------------------------------------------------------------------------
__global__ __launch_bounds__(256) void k_prep(
    const float* __restrict__ w1, const float* __restrict__ w2,
    unsigned short* __restrict__ Wpack2, unsigned short* __restrict__ Wpack1) {
  int i = blockIdx.x * 256 + threadIdx.x;
  if (i < 9216) {
    int j = i & 7;
    int lane = (i >> 3) & 63;
    int Mt = (i >> 9) & 1;
    int g = i >> 10;          // dx*3 + s
    int s = g % 3, dx = g / 3;
    int oc = Mt * 16 + (lane & 15);
    int kr = s * 32 + (lane >> 4) * 8 + j;
    float w = 0.f;
    if (oc < 27 && kr < 72) {
      int ci = kr / 9, rm = kr % 9, dzr = rm / 3, dyr = rm % 3;
      w = w2[(oc * 8 + ci) * 27 + dzr * 9 + dyr * 3 + dx];
    }
    __hip_bfloat16 hv = __float2bfloat16(w);
    Wpack2[i] = *(unsigned short*)&hv;
  }
  int jj = i - 9216;
  if (jj >= 0 && jj < 4608) {
    int j = jj & 7;
    int lane = (jj >> 3) & 63;
    int g = jj >> 9;          // dx*3 + s
    int s = g % 3, dx = g / 3;
    int oc = lane & 15;
    int kr = s * 32 + (lane >> 4) * 8 + j;
    float w = 0.f;
    if (oc < 8 && kr < 72) {
      int ci = kr / 9, rm = kr % 9, dzr = rm / 3, dyr = rm % 3;
      w = w1[(oc * 8 + ci) * 27 + dzr * 9 + dyr * 3 + dx];
    }
    __hip_bfloat16 hv = __float2bfloat16(w);
    Wpack1[jj] = *(unsigned short*)&hv;
  }
}

// ---------------------------------------------------------------------------
// Kernel 1: conv3d(x, w1) + bias + ReLU (8 -> 8) as implicit-GEMM MFMA
// (the structure correctness-proven by R4's k_conv2). Block = one (z,y) row,
// 4 waves x 2 N-tiles of 16 voxels; M = 16 (8 used). x staged fp32->bf16.
// ---------------------------------------------------------------------------
__global__ __launch_bounds__(256) void k_conv1m(
    const float* __restrict__ x, const unsigned short* __restrict__ Wpack1,
    const float* __restrict__ b1, __hip_bfloat16* __restrict__ hb) {
  __shared__ __align__(16) unsigned short xT[XT * PK];
  const int tid  = threadIdx.x;
  const int lane = tid & 63;
  const int wv   = tid >> 6;
  const int z0 = blockIdx.x >> 7;
  const int y0 = blockIdx.x & 127;

  // Weights -> VGPRs: 9 x bf16x8 (36 VGPR)
  bf16x8 wf[3][3];
  {
    const bf16x8* wp = (const bf16x8*)Wpack1;
#pragma unroll
    for (int dx = 0; dx < 3; ++dx)
#pragma unroll
      for (int s = 0; s < 3; ++s)
        wf[dx][s] = wp[(dx * 3 + s) * 64 + lane];
  }

  // Zero-fill LDS (kr pad + out-of-volume cells must be 0)
  {
    uint4 z4 = make_uint4(0u, 0u, 0u, 0u);
    uint4* p = (uint4*)xT;
#pragma unroll 1
    for (int i = tid; i < XT * PK / 8; i += 256) p[i] = z4;
  }
  __syncthreads();

  // Stage xT[xi][r]: r = ci*9 + dzrel*3 + dyrel; xi = x+1
#pragma unroll 1
  for (int c = tid; c < 72 * XT; c += 256) {
    int r  = c / XT;
    int xi = c - r * XT;
    int ci = r / 9, rm = r % 9, dzr = rm / 3, dyr = rm % 3;
    int z = z0 + dzr - 1, y = y0 + dyr - 1, xg = xi - 1;
    unsigned short v = 0;
    if ((unsigned)z < 128u && (unsigned)y < 128u && (unsigned)xg < 128u) {
      __hip_bfloat16 hv =
          __float2bfloat16(x[((size_t)(ci * 128 + z) * 128 + y) * 128 + xg]);
      v = *(unsigned short*)&hv;
    }
    xT[xi * PK + r] = v;
  }
  __syncthreads();

  f32x4 acc[2];
#pragma unroll
  for (int nt = 0; nt < 2; ++nt) acc[nt] = (f32x4){0.f, 0.f, 0.f, 0.f};

  const int n = lane & 15;
  const int q = lane >> 4;
  const int xbase = wv * 32 + n;

#pragma unroll
  for (int dx = 0; dx < 3; ++dx) {
#pragma unroll
    for (int s = 0; s < 3; ++s) {
      bf16x8 bfr[2];
#pragma unroll
      for (int nt = 0; nt < 2; ++nt) {
        int off = (xbase + nt * 16 + dx) * PK + s * 32 + q * 8;
        bfr[nt] = *(const bf16x8*)&xT[off];
      }
#pragma unroll
      for (int nt = 0; nt < 2; ++nt)
        acc[nt] = __builtin_amdgcn_mfma_f32_16x16x32_bf16(
            wf[dx][s], bfr[nt], acc[nt], 0, 0, 0);
    }
  }

  // Epilogue: +bias, ReLU, bf16 store. D: row(oc) = q*4+r, col(vox) = n.
  const int voxrow = (z0 * 128 + y0) * 128;
  if (q < 2) {
#pragma unroll
    for (int nt = 0; nt < 2; ++nt) {
      const int vox = voxrow + wv * 32 + nt * 16 + n;
#pragma unroll
      for (int r = 0; r < 4; ++r) {
        int oc = q * 4 + r;  // < 8
        float h = fmaxf(acc[nt][r] + b1[oc], 0.f);
        hb[(size_t)oc * DHW + vox] = __float2bfloat16(h);
      }
    }
  }
}

// ---------------------------------------------------------------------------
// Kernel 2: conv3d(h, w2) (8 -> 27) + fused L1 norm, implicit-GEMM MFMA
// (unchanged from R4).
// ---------------------------------------------------------------------------
__global__ __launch_bounds__(256) void k_conv2(
    const __hip_bfloat16* __restrict__ hb,
    const unsigned short* __restrict__ Wpack,
    __hip_bfloat16* __restrict__ wn) {
  __shared__ __align__(16) unsigned short hT[XT * PK];
  const int tid  = threadIdx.x;
  const int lane = tid & 63;
  const int wv   = tid >> 6;
  const int z0 = blockIdx.x >> 7;
  const int y0 = blockIdx.x & 127;

  bf16x8 wf[3][3][2];
  {
    const bf16x8* wp = (const bf16x8*)Wpack;
#pragma unroll
    for (int dx = 0; dx < 3; ++dx)
#pragma unroll
      for (int s = 0; s < 3; ++s)
#pragma unroll
        for (int mt = 0; mt < 2; ++mt)
          wf[dx][s][mt] = wp[((dx * 3 + s) * 2 + mt) * 64 + lane];
  }

  {
    uint4 z4 = make_uint4(0u, 0u, 0u, 0u);
    uint4* p = (uint4*)hT;
#pragma unroll 1
    for (int i = tid; i < XT * PK / 8; i += 256) p[i] = z4;
  }
  __syncthreads();

#pragma unroll 1
  for (int c = tid; c < 72 * XT; c += 256) {
    int r  = c / XT;
    int xi = c - r * XT;
    int ci = r / 9, rm = r % 9, dzr = rm / 3, dyr = rm % 3;
    int z = z0 + dzr - 1, y = y0 + dyr - 1, xg = xi - 1;
    unsigned short v = 0;
    if ((unsigned)z < 128u && (unsigned)y < 128u && (unsigned)xg < 128u)
      v = *(const unsigned short*)&hb[((size_t)(ci * 128 + z) * 128 + y) * 128 + xg];
    hT[xi * PK + r] = v;
  }
  __syncthreads();

  f32x4 acc[2][2];  // [nt][mt]
#pragma unroll
  for (int nt = 0; nt < 2; ++nt)
#pragma unroll
    for (int mt = 0; mt < 2; ++mt) acc[nt][mt] = (f32x4){0.f, 0.f, 0.f, 0.f};

  const int n = lane & 15;
  const int q = lane >> 4;
  const int xbase = wv * 32 + n;

#pragma unroll
  for (int dx = 0; dx < 3; ++dx) {
#pragma unroll
    for (int s = 0; s < 3; ++s) {
      bf16x8 bfr[2];
#pragma unroll
      for (int nt = 0; nt < 2; ++nt) {
        int off = (xbase + nt * 16 + dx) * PK + s * 32 + q * 8;
        bfr[nt] = *(const bf16x8*)&hT[off];
      }
#pragma unroll
      for (int mt = 0; mt < 2; ++mt)
#pragma unroll
        for (int nt = 0; nt < 2; ++nt)
          acc[nt][mt] = __builtin_amdgcn_mfma_f32_16x16x32_bf16(
              wf[dx][s][mt], bfr[nt], acc[nt][mt], 0, 0, 0);
    }
  }

  const int voxrow = (z0 * 128 + y0) * 128;
#pragma unroll
  for (int nt = 0; nt < 2; ++nt) {
    float ns = 0.f;
#pragma unroll
    for (int r = 0; r < 4; ++r) ns += fabsf(acc[nt][0][r]);
#pragma unroll
    for (int r = 0; r < 4; ++r) {
      int oc = 16 + q * 4 + r;
      ns += (oc < 27) ? fabsf(acc[nt][1][r]) : 0.f;
    }
    ns += __shfl_xor(ns, 16);
    ns += __shfl_xor(ns, 32);
    float sc = 1.f / fmaxf(ns, 1e-12f);
    const int vox = voxrow + wv * 32 + nt * 16 + n;
#pragma unroll
    for (int r = 0; r < 4; ++r) {
      int oc = q * 4 + r;
      wn[(size_t)oc * DHW + vox] = __float2bfloat16(acc[nt][0][r] * sc);
    }
#pragma unroll
    for (int r = 0; r < 4; ++r) {
      int oc = 16 + q * 4 + r;
      if (oc < 27)
        wn[(size_t)oc * DHW + vox] = __float2bfloat16(acc[nt][1][r] * sc);
    }
  }
}

// ---------------------------------------------------------------------------
// Kernel 3: one adaptive 3x3x3 conv pass (unchanged; profiled next round).
// ---------------------------------------------------------------------------
__global__ __launch_bounds__(256) void k_adapt(
    const float* __restrict__ in, const __hip_bfloat16* __restrict__ wn,
    float* __restrict__ out) {
  const int idx = blockIdx.x * 256 + threadIdx.x;
  const int d = idx >> 14;
  const int rem = idx & (HW2 - 1);
  const int hh = rem >> 7;
  const int ww = rem & 127;

  int offs[27];
  unsigned mask = 0;
  {
    int t = 0;
#pragma unroll
    for (int dz = -1; dz <= 1; ++dz) {
      int zz = d + dz; bool okz = (unsigned)zz < 128u; int zc = okz ? zz : d;
#pragma unroll
      for (int dy = -1; dy <= 1; ++dy) {
        int yy = hh + dy; bool oky = (unsigned)yy < 128u; int yc = oky ? yy : hh;
#pragma unroll
        for (int dx = -1; dx <= 1; ++dx) {
          int xx = ww + dx; bool okx = (unsigned)xx < 128u; int xc = okx ? xx : ww;
          offs[t] = (zc * HH + yc) * WW + xc;
          if (okz && oky && okx) mask |= (1u << t);
          ++t;
        }
      }
    }
  }

  float wt[27];
#pragma unroll
  for (int t = 0; t < 27; ++t)
    wt[t] = __bfloat162float(wn[(size_t)t * DHW + idx]);

#pragma unroll 1
  for (int c = 0; c < 8; ++c) {
    const float* base = in + (size_t)c * DHW;
    float a = 0.0f;
#pragma unroll
    for (int t = 0; t < 27; ++t) {
      float v = base[offs[t]];
      v = ((mask >> t) & 1u) ? v : 0.0f;
      a = fmaf(v, wt[t], a);
    }
    out[(size_t)c * DHW + idx] = a;
  }
}

// ---------------------------------------------------------------------------
extern "C" void kernel_launch(void* const* d_in, const int* in_sizes, int n_in,
                              void* d_out, int out_size, void* d_ws, size_t ws_size,
                              hipStream_t stream) {
  const float* x  = (const float*)d_in[0];
  const float* w1 = (const float*)d_in[1];
  const float* b1 = (const float*)d_in[2];
  const float* w2 = (const float*)d_in[3];
  float* out = (float*)d_out;

  // Workspace: hb bf16 32MiB | wn bf16 108MiB | tb fp32 64MiB | Wpack2 | Wpack1
  char* ws = (char*)d_ws;
  __hip_bfloat16* hb = (__hip_bfloat16*)ws;
  __hip_bfloat16* wn = (__hip_bfloat16*)(ws + (size_t)CIN * DHW * 2);
  float* tb = (float*)(ws + (size_t)CIN * DHW * 2 + (size_t)27 * DHW * 2);
  unsigned short* Wpack2 = (unsigned short*)(ws + (size_t)CIN * DHW * 2 +
                                             (size_t)27 * DHW * 2 +
                                             (size_t)CIN * DHW * 4);
  unsigned short* Wpack1 = Wpack2 + 9216;

  dim3 blk(256);
  k_prep<<<54, blk, 0, stream>>>(w1, w2, Wpack2, Wpack1);
  k_conv1m<<<128 * 128, blk, 0, stream>>>(x, Wpack1, b1, hb);
  k_conv2<<<128 * 128, blk, 0, stream>>>(hb, Wpack2, wn);
  // adaptive ping-pong: x -> out -> tb -> out (d_out doubles as scratch)
  k_adapt<<<DHW / 256, blk, 0, stream>>>(x, wn, out);
  k_adapt<<<DHW / 256, blk, 0, stream>>>(out, wn, tb);
  k_adapt<<<DHW / 256, blk, 0, stream>>>(tb, wn, out);
}

// Round 6
// 584.681 us; speedup vs baseline: 22.2823x; 1.5786x over previous
//
#include <hip/hip_runtime.h>
#include <hip/hip_bf16.h>

// Geometry (fixed): B=1, C=8, D=H=W=128.
constexpr int HW2 = 16384;
constexpr int DHW = 2097152;

// MFMA staging: LDS cell = 8 ci (bf16, 16 B) at (g = dz*3+dy group, xi).
// Pitch 13 groups (208 B): b128 lane-stride 52 words -> 8 lanes tile all 32
// banks exactly once => conflict-free staging writes AND fragment reads.
constexpr int PKG = 13;   // groups per xi row (9 used + 3 K-pad + 1 pitch pad)
constexpr int XT  = 130;  // staged x extent: x = -1 .. 128

typedef short bf16x8 __attribute__((ext_vector_type(8)));  // 8 bf16 = 4 VGPR
typedef float f32x4  __attribute__((ext_vector_type(4)));

__device__ inline unsigned short f2b(float f) {
  __hip_bfloat16 h = __float2bfloat16(f);
  return *(unsigned short*)&h;
}
__device__ inline float b2f(unsigned short u) {
  __hip_bfloat16 h = *(__hip_bfloat16*)&u;
  return __bfloat162float(h);
}

// ---------------------------------------------------------------------------
// Prep: pack w1/w2 into MFMA A-fragment order, bf16, dx-split.
//   k = s*32 + q*8 + j  ->  g = s*4+q (= (dz)*3+(dy), <9 valid), ci = j.
//   Wpack2: [(dx*3+s)*2+Mt][lane][j], oc = Mt*16+(lane&15) (<27)
//   Wpack1: [dx*3+s][lane][j],        oc = lane&15 (<8)
// ---------------------------------------------------------------------------
__global__ __launch_bounds__(256) void k_prep(
    const float* __restrict__ w1, const float* __restrict__ w2,
    unsigned short* __restrict__ Wpack2, unsigned short* __restrict__ Wpack1) {
  int i = blockIdx.x * 256 + threadIdx.x;
  if (i < 9216) {
    int j = i & 7;
    int lane = (i >> 3) & 63;
    int Mt = (i >> 9) & 1;
    int g2 = i >> 10;         // dx*3 + s
    int s = g2 % 3, dx = g2 / 3;
    int oc = Mt * 16 + (lane & 15);
    int kr = s * 32 + (lane >> 4) * 8 + j;
    int ci = kr & 7, g = kr >> 3;
    float w = 0.f;
    if (oc < 27 && g < 9) {
      int dzr = g / 3, dyr = g % 3;
      w = w2[(oc * 8 + ci) * 27 + dzr * 9 + dyr * 3 + dx];
    }
    Wpack2[i] = f2b(w);
  }
  int jj = i - 9216;
  if (jj >= 0 && jj < 4608) {
    int j = jj & 7;
    int lane = (jj >> 3) & 63;
    int g2 = jj >> 9;         // dx*3 + s
    int s = g2 % 3, dx = g2 / 3;
    int oc = lane & 15;
    int kr = s * 32 + (lane >> 4) * 8 + j;
    int ci = kr & 7, g = kr >> 3;
    float w = 0.f;
    if (oc < 8 && g < 9) {
      int dzr = g / 3, dyr = g % 3;
      w = w1[(oc * 8 + ci) * 27 + dzr * 9 + dyr * 3 + dx];
    }
    Wpack1[jj] = f2b(w);
  }
}

// ---------------------------------------------------------------------------
// Transpose x: [ci][z][y][x] fp32 -> [z][y][x][ci] bf16 (16 B/voxel, b128able)
// ---------------------------------------------------------------------------
__global__ __launch_bounds__(256) void k_xpose(
    const float* __restrict__ x, unsigned short* __restrict__ xb) {
  int idx = blockIdx.x * 256 + threadIdx.x;  // voxel
  unsigned v[4];
#pragma unroll
  for (int p = 0; p < 4; ++p) {
    unsigned lo = f2b(x[(size_t)(2 * p) * DHW + idx]);
    unsigned hi = f2b(x[(size_t)(2 * p + 1) * DHW + idx]);
    v[p] = lo | (hi << 16);
  }
  uint4 o = make_uint4(v[0], v[1], v[2], v[3]);
  ((uint4*)xb)[idx] = o;
}

// ---------------------------------------------------------------------------
// Kernel 1: conv3d(x, w1) + bias + ReLU (8 -> 8), implicit-GEMM MFMA.
// Block = one (z,y) row; staging = 1560 uint4 cells (coalesced b128 global ->
// conflict-free b128 LDS). Output hb in [vox][ci] layout (feeds conv2 staging).
// ---------------------------------------------------------------------------
__global__ __launch_bounds__(256) void k_conv1m(
    const unsigned short* __restrict__ xb,
    const unsigned short* __restrict__ Wpack1,
    const float* __restrict__ b1, unsigned short* __restrict__ hb) {
  __shared__ __align__(16) unsigned short T[XT * PKG * 8];
  const int tid  = threadIdx.x;
  const int lane = tid & 63;
  const int wv   = tid >> 6;
  const int z0 = blockIdx.x >> 7;
  const int y0 = blockIdx.x & 127;

  bf16x8 wf[3][3];
  {
    const bf16x8* wp = (const bf16x8*)Wpack1;
#pragma unroll
    for (int dx = 0; dx < 3; ++dx)
#pragma unroll
      for (int s = 0; s < 3; ++s)
        wf[dx][s] = wp[(dx * 3 + s) * 64 + lane];
  }

  const uint4* src = (const uint4*)xb;
  uint4* dst = (uint4*)T;
#pragma unroll 1
  for (int c = tid; c < 12 * XT; c += 256) {
    int g  = c / XT;          // 0..11
    int xi = c - g * XT;
    uint4 v = make_uint4(0u, 0u, 0u, 0u);
    if (g < 9) {
      int z = z0 + g / 3 - 1, y = y0 + g % 3 - 1, xg = xi - 1;
      if ((unsigned)z < 128u && (unsigned)y < 128u && (unsigned)xg < 128u)
        v = src[(z * 128 + y) * 128 + xg];
    }
    dst[xi * PKG + g] = v;
  }
  __syncthreads();

  f32x4 acc[2];
#pragma unroll
  for (int nt = 0; nt < 2; ++nt) acc[nt] = (f32x4){0.f, 0.f, 0.f, 0.f};

  const int n = lane & 15;
  const int q = lane >> 4;
  const int xbase = wv * 32 + n;

#pragma unroll
  for (int dx = 0; dx < 3; ++dx) {
#pragma unroll
    for (int s = 0; s < 3; ++s) {
      bf16x8 bfr[2];
#pragma unroll
      for (int nt = 0; nt < 2; ++nt) {
        int off = ((xbase + nt * 16 + dx) * PKG + (s * 4 + q)) * 8;
        bfr[nt] = *(const bf16x8*)&T[off];
      }
#pragma unroll
      for (int nt = 0; nt < 2; ++nt)
        acc[nt] = __builtin_amdgcn_mfma_f32_16x16x32_bf16(
            wf[dx][s], bfr[nt], acc[nt], 0, 0, 0);
    }
  }

  // Epilogue: +bias, ReLU -> hb[vox*8 + oc] (ushort4 per lane-half)
  const int voxrow = (z0 * 128 + y0) * 128;
  if (q < 2) {
#pragma unroll
    for (int nt = 0; nt < 2; ++nt) {
      const int vox = voxrow + wv * 32 + nt * 16 + n;
      ushort4 o;
      o.x = f2b(fmaxf(acc[nt][0] + b1[q * 4 + 0], 0.f));
      o.y = f2b(fmaxf(acc[nt][1] + b1[q * 4 + 1], 0.f));
      o.z = f2b(fmaxf(acc[nt][2] + b1[q * 4 + 2], 0.f));
      o.w = f2b(fmaxf(acc[nt][3] + b1[q * 4 + 3], 0.f));
      *(ushort4*)(hb + (size_t)vox * 8 + q * 4) = o;
    }
  }
}

// ---------------------------------------------------------------------------
// Kernel 2: conv3d(h, w2) (8 -> 27) + fused L1 norm, implicit-GEMM MFMA.
// Same staging; epilogue (R4/R5-proven) writes wn in [oc][vox] bf16.
// ---------------------------------------------------------------------------
__global__ __launch_bounds__(256) void k_conv2(
    const unsigned short* __restrict__ hb,
    const unsigned short* __restrict__ Wpack2,
    unsigned short* __restrict__ wn) {
  __shared__ __align__(16) unsigned short T[XT * PKG * 8];
  const int tid  = threadIdx.x;
  const int lane = tid & 63;
  const int wv   = tid >> 6;
  const int z0 = blockIdx.x >> 7;
  const int y0 = blockIdx.x & 127;

  bf16x8 wf[3][3][2];
  {
    const bf16x8* wp = (const bf16x8*)Wpack2;
#pragma unroll
    for (int dx = 0; dx < 3; ++dx)
#pragma unroll
      for (int s = 0; s < 3; ++s)
#pragma unroll
        for (int mt = 0; mt < 2; ++mt)
          wf[dx][s][mt] = wp[((dx * 3 + s) * 2 + mt) * 64 + lane];
  }

  const uint4* src = (const uint4*)hb;
  uint4* dst = (uint4*)T;
#pragma unroll 1
  for (int c = tid; c < 12 * XT; c += 256) {
    int g  = c / XT;
    int xi = c - g * XT;
    uint4 v = make_uint4(0u, 0u, 0u, 0u);
    if (g < 9) {
      int z = z0 + g / 3 - 1, y = y0 + g % 3 - 1, xg = xi - 1;
      if ((unsigned)z < 128u && (unsigned)y < 128u && (unsigned)xg < 128u)
        v = src[(z * 128 + y) * 128 + xg];
    }
    dst[xi * PKG + g] = v;
  }
  __syncthreads();

  f32x4 acc[2][2];  // [nt][mt]
#pragma unroll
  for (int nt = 0; nt < 2; ++nt)
#pragma unroll
    for (int mt = 0; mt < 2; ++mt) acc[nt][mt] = (f32x4){0.f, 0.f, 0.f, 0.f};

  const int n = lane & 15;
  const int q = lane >> 4;
  const int xbase = wv * 32 + n;

#pragma unroll
  for (int dx = 0; dx < 3; ++dx) {
#pragma unroll
    for (int s = 0; s < 3; ++s) {
      bf16x8 bfr[2];
#pragma unroll
      for (int nt = 0; nt < 2; ++nt) {
        int off = ((xbase + nt * 16 + dx) * PKG + (s * 4 + q)) * 8;
        bfr[nt] = *(const bf16x8*)&T[off];
      }
#pragma unroll
      for (int mt = 0; mt < 2; ++mt)
#pragma unroll
        for (int nt = 0; nt < 2; ++nt)
          acc[nt][mt] = __builtin_amdgcn_mfma_f32_16x16x32_bf16(
              wf[dx][s][mt], bfr[nt], acc[nt][mt], 0, 0, 0);
    }
  }

  const int voxrow = (z0 * 128 + y0) * 128;
#pragma unroll
  for (int nt = 0; nt < 2; ++nt) {
    float ns = 0.f;
#pragma unroll
    for (int r = 0; r < 4; ++r) ns += fabsf(acc[nt][0][r]);
#pragma unroll
    for (int r = 0; r < 4; ++r) {
      int oc = 16 + q * 4 + r;
      ns += (oc < 27) ? fabsf(acc[nt][1][r]) : 0.f;
    }
    ns += __shfl_xor(ns, 16);
    ns += __shfl_xor(ns, 32);
    float sc = 1.f / fmaxf(ns, 1e-12f);
    const int vox = voxrow + wv * 32 + nt * 16 + n;
#pragma unroll
    for (int r = 0; r < 4; ++r) {
      int oc = q * 4 + r;
      wn[(size_t)oc * DHW + vox] = f2b(acc[nt][0][r] * sc);
    }
#pragma unroll
    for (int r = 0; r < 4; ++r) {
      int oc = 16 + q * 4 + r;
      if (oc < 27)
        wn[(size_t)oc * DHW + vox] = f2b(acc[nt][1][r] * sc);
    }
  }
}

// ---------------------------------------------------------------------------
// Kernel 3: adaptive 3x3x3 conv, 4 voxels (x0..x0+3) per thread.
// Per (dz,dy) group: 3 ushort4 weight loads + per-channel 6-float x-segment
// (float4 + 2 scalars) shared across the 3 dx taps.
// ---------------------------------------------------------------------------
__global__ __launch_bounds__(256) void k_adapt(
    const float* __restrict__ in, const unsigned short* __restrict__ wn,
    float* __restrict__ out) {
  const int t = blockIdx.x * 256 + threadIdx.x;  // [0, DHW/4)
  const int xg = (t & 31) * 4;
  const int rest = t >> 5;
  const int y = rest & 127;
  const int z = rest >> 7;
  const int vox0 = (z * 128 + y) * 128 + xg;

  float acc[8][4];
#pragma unroll
  for (int c = 0; c < 8; ++c)
#pragma unroll
    for (int v = 0; v < 4; ++v) acc[c][v] = 0.f;

#pragma unroll
  for (int g = 0; g < 9; ++g) {
    const int dz = g / 3 - 1, dy = g % 3 - 1;
    const int zz = z + dz, yy = y + dy;
    if ((unsigned)zz < 128u && (unsigned)yy < 128u) {
      float wt[3][4];
#pragma unroll
      for (int dxi = 0; dxi < 3; ++dxi) {
        ushort4 wv = *(const ushort4*)(wn + (size_t)(g * 3 + dxi) * DHW + vox0);
        wt[dxi][0] = b2f(wv.x);
        wt[dxi][1] = b2f(wv.y);
        wt[dxi][2] = b2f(wv.z);
        wt[dxi][3] = b2f(wv.w);
      }
      const int rowb = (zz * 128 + yy) * 128;
#pragma unroll
      for (int c = 0; c < 8; ++c) {
        const float* row = in + (size_t)c * DHW + rowb;
        float s_[6];
        float4 mid = *(const float4*)(row + xg);
        s_[1] = mid.x; s_[2] = mid.y; s_[3] = mid.z; s_[4] = mid.w;
        s_[0] = (xg > 0) ? row[xg - 1] : 0.f;
        s_[5] = (xg < 124) ? row[xg + 4] : 0.f;
#pragma unroll
        for (int dxi = 0; dxi < 3; ++dxi)
#pragma unroll
          for (int v = 0; v < 4; ++v)
            acc[c][v] = fmaf(s_[v + dxi], wt[dxi][v], acc[c][v]);
      }
    }
  }

#pragma unroll
  for (int c = 0; c < 8; ++c) {
    float4 o = make_float4(acc[c][0], acc[c][1], acc[c][2], acc[c][3]);
    *(float4*)(out + (size_t)c * DHW + vox0) = o;
  }
}

// ---------------------------------------------------------------------------
extern "C" void kernel_launch(void* const* d_in, const int* in_sizes, int n_in,
                              void* d_out, int out_size, void* d_ws, size_t ws_size,
                              hipStream_t stream) {
  const float* x  = (const float*)d_in[0];
  const float* w1 = (const float*)d_in[1];
  const float* b1 = (const float*)d_in[2];
  const float* w2 = (const float*)d_in[3];
  float* out = (float*)d_out;

  // Workspace: xb bf16 32MiB | hb bf16 32MiB | wn bf16 108MiB | tb fp32 64MiB
  //            | Wpack2 | Wpack1
  char* ws = (char*)d_ws;
  unsigned short* xb = (unsigned short*)ws;
  unsigned short* hb = (unsigned short*)(ws + (size_t)8 * DHW * 2);
  unsigned short* wn = (unsigned short*)(ws + (size_t)16 * DHW * 2);
  float* tb = (float*)(ws + (size_t)16 * DHW * 2 + (size_t)27 * DHW * 2);
  unsigned short* Wpack2 =
      (unsigned short*)(ws + (size_t)16 * DHW * 2 + (size_t)27 * DHW * 2 +
                        (size_t)8 * DHW * 4);
  unsigned short* Wpack1 = Wpack2 + 9216;

  dim3 blk(256);
  k_prep<<<54, blk, 0, stream>>>(w1, w2, Wpack2, Wpack1);
  k_xpose<<<DHW / 256, blk, 0, stream>>>(x, xb);
  k_conv1m<<<128 * 128, blk, 0, stream>>>(xb, Wpack1, b1, hb);
  k_conv2<<<128 * 128, blk, 0, stream>>>(hb, Wpack2, wn);
  // adaptive ping-pong: x -> out -> tb -> out
  k_adapt<<<DHW / 4 / 256, blk, 0, stream>>>(x, wn, out);
  k_adapt<<<DHW / 4 / 256, blk, 0, stream>>>(out, wn, tb);
  k_adapt<<<DHW / 4 / 256, blk, 0, stream>>>(tb, wn, out);
}